// Round 1
// baseline (193.832 us; speedup 1.0000x reference)
//
#include <hip/hip_runtime.h>

// ---------------------------------------------------------------------------
// TripletContrastiveLoss on MI355X (gfx950)  — Round 13
// Big lever: tile_mindist rewritten from the m97-class 128^2/4-wave/
// drain-every-step structure (measured 370 TF, MfmaUtil 14.8%) to the
// 8-phase-class schedule (guide §5 template, T2+T3+T4+T5):
//   * 256x256 tile, 8 waves, wave-tile 128x64 (LDS-BW balanced)
//   * BK=32, FOUR LDS K-buffers (128 KiB), prefetch distance 2 K-tiles
//   * steady-state s_waitcnt vmcnt(4) — never 0 in the main loop (T4)
//   * raw s_barrier (NOT __syncthreads — that drains vmcnt), sched_barrier(0)
//     fence at the buffer-switch (rule 18), setprio around MFMA (T5)
//   * T2 bank swizzle, both-sides (rule 21): global source chunk pre-swizzled
//     with the same involution (chunk ^= row&3) the ds_read_b128 applies
// Secondary: compute_slots loads coalesced + wave-shuffle scan (slot order is
// an arbitrary bijection, so re-enumeration is free).
// normalize_rows / reduce_loss / finalize / launcher layout unchanged.
// ---------------------------------------------------------------------------

#define B_ROWS 8192
#define DIM    1024

typedef __bf16 bf16x8 __attribute__((ext_vector_type(8)));
typedef float  f32x4  __attribute__((ext_vector_type(4)));

__device__ __forceinline__ unsigned short f2bf_rne(float x) {
    unsigned u = __float_as_uint(x);
    unsigned r = (u + 0x7FFFu + ((u >> 16) & 1u)) >> 16;
    return (unsigned short)r;
}
__device__ __forceinline__ float bf2f(unsigned short h) {
    return __uint_as_float(((unsigned)h) << 16);
}

// Async global->LDS, 16 B per lane. LDS dest must be wave-uniform; HW places
// lane i at base + 16*i. Global source IS per-lane (swizzle goes there).
__device__ __forceinline__ void async_copy16(const void* g, void* l) {
    __builtin_amdgcn_global_load_lds(
        (const __attribute__((address_space(1))) unsigned int*)g,
        (__attribute__((address_space(3))) unsigned int*)l,
        16, 0, 0);
}

// ---------------------------------------------------------------------------
// Kernel 0: slot assignment. 1 block x 256 threads, 32 rows/thread, rows
// re-enumerated t + 256*i so loads/stores are lane-coalesced. Any bijection
// A->[0,nA), F->[nA,8192) is valid (epilogue/reduction are order-free).
// Prefix over per-thread counts via wave-0 shuffle scan (no serial 256-loop).
// cnt[0] = nA. slotOf overlays posmin (clobbered later by 0xFF memset).
// ---------------------------------------------------------------------------
__global__ __launch_bounds__(256) void compute_slots(
    const int* __restrict__ dom, int* __restrict__ slotOf,
    unsigned* __restrict__ cnt)
{
    __shared__ int cnts[256];
    __shared__ int base[257];
    const int t = threadIdx.x;

    unsigned mask = 0u; int c = 0;
    #pragma unroll
    for (int i = 0; i < 32; ++i) {
        const int isA = (dom[t + 256 * i] == 0) ? 1 : 0;
        mask |= ((unsigned)isA) << i;
        c += isA;
    }
    cnts[t] = c;
    __syncthreads();
    if (t < 64) {   // wave 0: 4 counts/lane, inclusive shuffle scan
        const int c0 = cnts[4 * t + 0], c1 = cnts[4 * t + 1];
        const int c2 = cnts[4 * t + 2], c3 = cnts[4 * t + 3];
        const int s4 = c0 + c1 + c2 + c3;
        int sc = s4;
        #pragma unroll
        for (int d = 1; d < 64; d <<= 1) {
            const int o = __shfl_up(sc, d);
            if (t >= d) sc += o;
        }
        const int b = sc - s4;                  // exclusive prefix
        base[4 * t + 0] = b;
        base[4 * t + 1] = b + c0;
        base[4 * t + 2] = b + c0 + c1;
        base[4 * t + 3] = b + c0 + c1 + c2;
        if (t == 63) { base[256] = sc; cnt[0] = (unsigned)sc; }  // nA
    }
    __syncthreads();
    const int nA = base[256];
    int aB = base[t];
    int fB = nA + t * 32 - base[t];   // F rows before thread t in (t,i) order
    #pragma unroll
    for (int i = 0; i < 32; ++i) {
        const int isA = (mask >> i) & 1;
        slotOf[t + 256 * i] = isA ? aB : fB;
        aB += isA;
        fB += 1 - isA;
    }
}

// ---------------------------------------------------------------------------
// Kernel 1: one row per WAVE. 2048 blocks x 256 threads (4 waves). Wave-local
// shuffle reductions only. L2-normalize fp32, round to bf16, scatter to slot.
// sqG[slot] = sum of squares of the bf16-ROUNDED row.  (unchanged)
// ---------------------------------------------------------------------------
__global__ __launch_bounds__(256) void normalize_rows(
    const float* __restrict__ feat, const int* __restrict__ labels,
    const int* __restrict__ slotOf, unsigned short* __restrict__ G,
    int* __restrict__ labG, float* __restrict__ sqG)
{
    const int wv = threadIdx.x >> 6, lane = threadIdx.x & 63;
    const int row = blockIdx.x * 4 + wv;

    const float4* src = (const float4*)(feat + (size_t)row * DIM);
    float4 v[4];
    float ss = 0.0f;
    #pragma unroll
    for (int j = 0; j < 4; ++j) {
        v[j] = src[j * 64 + lane];
        ss += v[j].x * v[j].x + v[j].y * v[j].y + v[j].z * v[j].z + v[j].w * v[j].w;
    }
    #pragma unroll
    for (int s = 32; s > 0; s >>= 1) ss += __shfl_xor(ss, s);
    const float inv = 1.0f / fmaxf(sqrtf(ss), 1e-12f);

    const int slot = slotOf[row];
    unsigned short ub[16];
    float ss2 = 0.0f;
    #pragma unroll
    for (int j = 0; j < 4; ++j) {
        const float f0 = v[j].x * inv, f1 = v[j].y * inv,
                    f2 = v[j].z * inv, f3 = v[j].w * inv;
        ub[j * 4 + 0] = f2bf_rne(f0); ub[j * 4 + 1] = f2bf_rne(f1);
        ub[j * 4 + 2] = f2bf_rne(f2); ub[j * 4 + 3] = f2bf_rne(f3);
        #pragma unroll
        for (int q = 0; q < 4; ++q) {
            const float fr = bf2f(ub[j * 4 + q]);
            ss2 += fr * fr;
        }
    }
    #pragma unroll
    for (int s = 32; s > 0; s >>= 1) ss2 += __shfl_xor(ss2, s);
    if (lane == 0) {
        sqG[slot]  = ss2;
        labG[slot] = labels[row];
    }
    ushort4* dst = (ushort4*)(G + (size_t)slot * DIM);
    #pragma unroll
    for (int j = 0; j < 4; ++j) {
        ushort4 pk;
        pk.x = ub[j * 4 + 0]; pk.y = ub[j * 4 + 1];
        pk.z = ub[j * 4 + 2]; pk.w = ub[j * 4 + 3];
        dst[j * 64 + lane] = pk;
    }
}

// ---------------------------------------------------------------------------
// Kernel 2: 256x256 tiles, 8 waves (2M x 4N, wave-tile 128x64 via 8x4 of
// 16x16x32 bf16 MFMA), K=1024 in 32 K-tiles of BK=32.
//
// Pipeline (T3/T4): 4 LDS buffers (kt & 3). Iteration kt:
//   phase 0: ds_read a[0..3] + f[0..3] (swizzled) | issue kt+2 staging (8KB/wv
//            share = 4 x global_load_lds) | s_barrier | 16 MFMA (setprio)
//   phase 1: ds_read a[4..7] | s_waitcnt vmcnt(4)  <- kt+1 resident, kt+2
//            stays IN FLIGHT (never drain to 0 mid-loop) | s_barrier |
//            16 MFMA | s_barrier | sched_barrier(0) fence (rule 18)
// Swizzle (T2, rule 21): LDS rows are 64 B = 4 x 16B chunks; ds_read uses
// chunk = quad ^ (row&3); staging pre-applies the same involution to the
// GLOBAL source chunk so the linear global_load_lds lands data correctly.
// Epilogue: per-anchor-row min d^2 -> atomicMin (uint order), as before.
// ---------------------------------------------------------------------------
__global__ __launch_bounds__(512, 2) void tile_mindist(
    const unsigned short* __restrict__ G, const int* __restrict__ labG,
    const float* __restrict__ sqG, const unsigned* __restrict__ cnt,
    unsigned* __restrict__ posmin, unsigned* __restrict__ negmin)
{
    const int nA = (int)cnt[0];
    const int nF = B_ROWS - nA;
    const int nTA = (nA + 255) >> 8;
    const int nTF = (nF + 255) >> 8;
    const int total = nTA * nTF;

    // [buf 0..3][A=0/F=1][256 rows x 32 shorts (64 B rows)] = 131072 B
    __shared__ __align__(16) unsigned short S[4][2][256 * 32];

    const int t = threadIdx.x;
    const int lane = t & 63, w = t >> 6;         // 8 waves
    const int wm = w >> 2, wn = w & 3;           // 2 (A, x128) x 4 (F, x64)
    const int l15 = lane & 15, quad = lane >> 4;
    const int ch8 = (quad ^ (l15 & 3)) * 8;      // swizzled read chunk (shorts)

    // staging: 1 KiB chunk = 16 rows x 64 B; lane -> row lane>>2, phys chunk
    // lane&3; SOURCE chunk = (lane&3) ^ (row&3)  (same involution as read)
    const int srow  = lane >> 2;
    const int scs16 = (((lane & 3) ^ (srow & 3)) << 4);

    const char* Gb = (const char*)G;
    const int rAq = wm * 128 + l15;              // A frag row base in tile
    const int rFq = wn * 64  + l15;              // F frag row base in tile

    for (int tile = blockIdx.x; tile < total; tile += gridDim.x) {
        const int tx = tile % nTA;
        const int ty = tile / nTA;
        const int rowA0 = tx << 8;
        const int rowF0 = nA + (ty << 8);

        const int arow = rowA0 + 32 * w + srow;  // +16h; always < 8192
        const int frow = rowF0 + 32 * w + srow;  // clamp per chunk

        f32x4 acc[8][4] = {};

        // ---- prologue: stage K-tiles 0 and 1 into buffers 0,1 (8 loads/wave)
        #pragma unroll
        for (int p = 0; p < 2; ++p) {
            const int ktB = p * 64;
            #pragma unroll
            for (int h = 0; h < 2; ++h) {
                const char* gA = Gb + (size_t)(arow + 16 * h) * 2048 + ktB + scs16;
                async_copy16(gA, &S[p][0][(32 * w + 16 * h) * 32]);
                int rF = frow + 16 * h; if (rF > B_ROWS - 1) rF = B_ROWS - 1;
                const char* gF = Gb + (size_t)rF * 2048 + ktB + scs16;
                async_copy16(gF, &S[p][1][(32 * w + 16 * h) * 32]);
            }
        }
        asm volatile("s_waitcnt vmcnt(4)" ::: "memory");   // K-tile 0 resident
        __builtin_amdgcn_s_barrier();
        __builtin_amdgcn_sched_barrier(0);

        for (int kt = 0; kt < 32; ++kt) {
            const unsigned short* SA = &S[kt & 3][0][0];
            const unsigned short* SF = &S[kt & 3][1][0];

            bf16x8 a[8], f[4];
            // ---------------- phase 0: wave A-rows 0-63 ------------------
            #pragma unroll
            for (int fm = 0; fm < 4; ++fm)
                a[fm] = *(const bf16x8*)(SA + (rAq + fm * 16) * 32 + ch8);
            #pragma unroll
            for (int fn = 0; fn < 4; ++fn)
                f[fn] = *(const bf16x8*)(SF + (rFq + fn * 16) * 32 + ch8);
            if (kt < 30) {                     // stage K-tile kt+2
                unsigned short* DA = &S[(kt + 2) & 3][0][0];
                unsigned short* DF = &S[(kt + 2) & 3][1][0];
                const int ktB = (kt + 2) * 64;
                #pragma unroll
                for (int h = 0; h < 2; ++h) {
                    const char* gA = Gb + (size_t)(arow + 16 * h) * 2048 + ktB + scs16;
                    async_copy16(gA, DA + (32 * w + 16 * h) * 32);
                    int rF = frow + 16 * h; if (rF > B_ROWS - 1) rF = B_ROWS - 1;
                    const char* gF = Gb + (size_t)rF * 2048 + ktB + scs16;
                    async_copy16(gF, DF + (32 * w + 16 * h) * 32);
                }
            }
            __builtin_amdgcn_s_barrier();
            __builtin_amdgcn_s_setprio(1);
            #pragma unroll
            for (int fm = 0; fm < 4; ++fm)
                #pragma unroll
                for (int fn = 0; fn < 4; ++fn)
                    acc[fm][fn] = __builtin_amdgcn_mfma_f32_16x16x32_bf16(
                        a[fm], f[fn], acc[fm][fn], 0, 0, 0);
            __builtin_amdgcn_s_setprio(0);
            __builtin_amdgcn_s_barrier();

            // ---------------- phase 1: wave A-rows 64-127 ----------------
            #pragma unroll
            for (int fm = 4; fm < 8; ++fm)
                a[fm] = *(const bf16x8*)(SA + (rAq + fm * 16) * 32 + ch8);
            // kt+1 must be resident before next iteration reads it; kt+2's 4
            // loads stay in flight (counted wait — the T4 lever).
            if (kt < 30) { asm volatile("s_waitcnt vmcnt(4)" ::: "memory"); }
            else         { asm volatile("s_waitcnt vmcnt(0)" ::: "memory"); }
            __builtin_amdgcn_s_barrier();
            __builtin_amdgcn_s_setprio(1);
            #pragma unroll
            for (int fm = 4; fm < 8; ++fm)
                #pragma unroll
                for (int fn = 0; fn < 4; ++fn)
                    acc[fm][fn] = __builtin_amdgcn_mfma_f32_16x16x32_bf16(
                        a[fm], f[fn], acc[fm][fn], 0, 0, 0);
            __builtin_amdgcn_s_setprio(0);
            __builtin_amdgcn_s_barrier();
            __builtin_amdgcn_sched_barrier(0);   // fence: next-buf ds_reads stay below
        }

        // ---- epilogue. C/D layout: col = lane&15 (field), row = quad*4+reg.
        const float INFV = __uint_as_float(0x7f800000u);
        float sqf[4]; int lf_[4]; bool vf[4];
        #pragma unroll
        for (int fn = 0; fn < 4; ++fn) {
            const int rf = rowF0 + wn * 64 + fn * 16 + l15;
            vf[fn] = rf < B_ROWS;
            const int rc = vf[fn] ? rf : (B_ROWS - 1);
            sqf[fn] = sqG[rc];
            lf_[fn] = labG[rc];
        }
        #pragma unroll
        for (int fm = 0; fm < 8; ++fm) {
            #pragma unroll
            for (int r = 0; r < 4; ++r) {
                const int ra = rowA0 + wm * 128 + fm * 16 + quad * 4 + r;
                const bool va = ra < nA;
                const int rac = va ? ra : 0;
                const float sqa = sqG[rac];
                const int la_ = labG[rac];
                float pmin = INFV, nmin = INFV;
                #pragma unroll
                for (int fn = 0; fn < 4; ++fn) {
                    const float dd = fmaxf(sqa + sqf[fn] - 2.0f * acc[fm][fn][r], 0.0f);
                    if (vf[fn]) {
                        if (la_ == lf_[fn]) pmin = fminf(pmin, dd);
                        else                nmin = fminf(nmin, dd);
                    }
                }
                #pragma unroll
                for (int s = 1; s < 16; s <<= 1) {
                    pmin = fminf(pmin, __shfl_xor(pmin, s));
                    nmin = fminf(nmin, __shfl_xor(nmin, s));
                }
                if (l15 == 0 && va) {
                    if (pmin < INFV) atomicMin(&posmin[ra], __float_as_uint(pmin));
                    if (nmin < INFV) atomicMin(&negmin[ra], __float_as_uint(nmin));
                }
            }
        }
        // No extra barrier needed: next tile's prologue targets bufs 0,1 (last
        // read at kt=28/29, fenced by kt=30/31 barriers all waves crossed).
    }
}

// ---------------------------------------------------------------------------
// Kernel 3: sqrt(d^2 mins) + hinge + sum/count. Untouched slots stay
// 0xFFFFFFFF and drop out as invalid.  (unchanged)
// ---------------------------------------------------------------------------
__global__ __launch_bounds__(256) void reduce_loss(
    const unsigned* __restrict__ posmin, const unsigned* __restrict__ negmin,
    float* __restrict__ accum)
{
    const int i = blockIdx.x * 256 + threadIdx.x;
    const unsigned up = posmin[i], un = negmin[i];
    float tl = 0.0f, c = 0.0f;
    if (up != 0xFFFFFFFFu && un != 0xFFFFFFFFu) {
        const float pd = sqrtf(__uint_as_float(up));
        const float nd = sqrtf(__uint_as_float(un));
        tl = fmaxf(pd - nd + 0.3f, 0.0f);
        c = 1.0f;
    }
    #pragma unroll
    for (int s = 32; s > 0; s >>= 1) {
        tl += __shfl_down(tl, s);
        c  += __shfl_down(c, s);
    }
    __shared__ float sb[8];
    const int lane = threadIdx.x & 63, w = threadIdx.x >> 6;
    if (lane == 0) { sb[w] = tl; sb[4 + w] = c; }
    __syncthreads();
    if (threadIdx.x == 0) {
        atomicAdd(&accum[0], sb[0] + sb[1] + sb[2] + sb[3]);
        atomicAdd(&accum[1], sb[4] + sb[5] + sb[6] + sb[7]);
    }
}

__global__ void finalize(const float* __restrict__ accum, float* __restrict__ out) {
    const float s = accum[0], c = accum[1];
    out[0] = (c > 0.0f) ? s / fmaxf(c, 1.0f) : 0.0f;
}

// ---------------------------------------------------------------------------
extern "C" void kernel_launch(void* const* d_in, const int* in_sizes, int n_in,
                              void* d_out, int out_size, void* d_ws, size_t ws_size,
                              hipStream_t stream) {
    const float* feat  = (const float*)d_in[0];
    const int* labels  = (const int*)d_in[1];
    const int* dom     = (const int*)d_in[2];
    float* out = (float*)d_out;

    char* ws = (char*)d_ws;
    // Workspace layout (bytes) — identical footprint to validated R4/R8 layout:
    unsigned short* G   = (unsigned short*)(ws);                 // 16,777,216
    int*      labG      = (int*)(ws + 16777216);                 //     32,768
    float*    sqG       = (float*)(ws + 16809984);               //     32,768
    unsigned* posmin    = (unsigned*)(ws + 16842752);            //     32,768
    unsigned* negmin    = (unsigned*)(ws + 16875520);            //     32,768
    unsigned* cnt       = (unsigned*)(ws + 16908288);            //  8 (nA)
    float*    accum     = (float*)(ws + 16908296);               //  8 (sum, count)
    // slotOf OVERLAYS posmin: written by compute_slots, consumed by
    // normalize_rows, then clobbered by the 0xFF memset (stream-ordered).
    int*      slotOf    = (int*)(ws + 16842752);

    hipMemsetAsync(cnt, 0, 16, stream);             // cnt + accum = 0

    compute_slots<<<1, 256, 0, stream>>>(dom, slotOf, cnt);
    normalize_rows<<<B_ROWS / 4, 256, 0, stream>>>(feat, labels, slotOf,
                                                   G, labG, sqG);

    hipMemsetAsync(posmin, 0xFF, 65536, stream);    // posmin+negmin = +inf bits

    // Max 256^2 tiles over all nA splits: ceil(a/256)*ceil((8192-a)/256) <= 272.
    // 128 KiB LDS -> 1 block/CU; extra blocks queue (dynamic balancing).
    tile_mindist<<<272, 512, 0, stream>>>(G, labG, sqG, cnt, posmin, negmin);

    reduce_loss<<<B_ROWS / 256, 256, 0, stream>>>(posmin, negmin, accum);
    finalize<<<1, 1, 0, stream>>>(accum, out);
}